// Round 1
// baseline (517.273 us; speedup 1.0000x reference)
//
#include <hip/hip_runtime.h>

// Block-circulant matmul via FFT:
//   y[b, i*256+t] = ifft_t( sum_j fft(x_d[b, j-block]) * conj(fft(W[i,j,:])) ) + bias
// B=8192, D=4096, BS=256, K_IN=K_OUT=16.
// Kernel 1: Wc[f][i][j] = conj(FFT_256(W[i,j,:]))[f] for f=0..128 into d_ws.
// Kernel 2: one block per row: load+scale by d -> 16 fwd FFTs (radix-4
// Stockham, LDS ping-pong) -> per-freq 16x16 complex matmul (f<=128, rest by
// conjugate symmetry, in-place column update) -> 16 inverse FFTs -> +bias.

#define TWO_PI 6.283185307179586476925286766559f

constexpr int BATCH = 8192;
constexpr int DDIM  = 4096;
constexpr int NFREQ = 129;   // 0..128 inclusive (real-input symmetry)

// One radix-4 Stockham stage over 16 independent length-256 FFTs laid out
// contiguously (FFT jj at [jj*256, jj*256+256)). 256 threads, 4 butterflies
// per thread. S in {1,4,16,64}. vsign=+1 forward (e^{-i}), -1 inverse.
template<int S, int LOG2S>
__device__ __forceinline__ void fft_stage4(const float* __restrict__ sr, const float* __restrict__ si,
                                           float* __restrict__ dr, float* __restrict__ di,
                                           const float* __restrict__ tabr, const float* __restrict__ tabi,
                                           int t, float vsign)
{
#pragma unroll
    for (int r = 0; r < 4; ++r) {
        int bt = r * 256 + t;
        int jj = bt >> 6;          // which FFT (0..15)
        int w  = bt & 63;          // butterfly id within FFT (0..63)
        int p  = w >> LOG2S;
        int q  = w & (S - 1);
        int base = jj << 8;
        int i0 = base + w;         // == base + q + S*p  (reads are stride-1)
        float ar = sr[i0],       ai = si[i0];
        float br = sr[i0 + 64],  bi = si[i0 + 64];
        float cr = sr[i0 + 128], ci = si[i0 + 128];
        float er = sr[i0 + 192], ei = si[i0 + 192];
        float apcr = ar + cr, apci = ai + ci;
        float amcr = ar - cr, amci = ai - ci;
        float bpdr = br + er, bpdi = bi + ei;
        float bmdr = br - er, bmdi = bi - ei;
        int o = base + q + 4 * S * p;
        dr[o] = apcr + bpdr;
        di[o] = apci + bpdi;
        // pre1 = amc - vsign*i*bmd ; pre3 = amc + vsign*i*bmd
        float p1r = amcr + vsign * bmdi, p1i = amci - vsign * bmdr;
        float p2r = apcr - bpdr,         p2i = apci - bpdi;
        float p3r = amcr - vsign * bmdi, p3i = amci + vsign * bmdr;
        int ti = p * S;  // twiddle index: exp(-+ 2*pi*i * p / n), n = 256/S
        float w1r = tabr[ti],     w1i = -vsign * tabi[ti];
        float w2r = tabr[2 * ti], w2i = -vsign * tabi[2 * ti];
        float w3r = tabr[3 * ti], w3i = -vsign * tabi[3 * ti];
        dr[o + S]     = p1r * w1r - p1i * w1i;
        di[o + S]     = p1r * w1i + p1i * w1r;
        dr[o + 2 * S] = p2r * w2r - p2i * w2i;
        di[o + 2 * S] = p2r * w2i + p2i * w2r;
        dr[o + 3 * S] = p3r * w3r - p3i * w3i;
        di[o + 3 * S] = p3r * w3i + p3i * w3r;
    }
}

// Precompute Wc[f][i][j] = conj(FFT(W[i,j,:]))[f] = sum_c W[i,j,c] e^{+2pi i f c/256}
// Grid: 256 blocks (one per (i,j)), 256 threads (f; only f<=128 stored).
__global__ __launch_bounds__(256) void wfft_kernel(const float* __restrict__ W,
                                                   float2* __restrict__ Wc)
{
    __shared__ float wblk[256];
    __shared__ float tabr[256], tabi[256];
    int t   = threadIdx.x;
    int blk = blockIdx.x;          // blk = i*16 + j
    wblk[t] = W[blk * 256 + t];
    float s, c;
    sincosf((float)t * (TWO_PI / 256.0f), &s, &c);
    tabr[t] = c; tabi[t] = s;
    __syncthreads();
    if (t < NFREQ) {
        float ar = 0.f, ai = 0.f;
        for (int cc = 0; cc < 256; ++cc) {
            int idx = (t * cc) & 255;
            float wv = wblk[cc];
            ar = fmaf(wv, tabr[idx], ar);
            ai = fmaf(wv, tabi[idx], ai);
        }
        int i = blk >> 4, j = blk & 15;
        Wc[(t * 16 + i) * 16 + j] = make_float2(ar, ai);
    }
}

__global__ __launch_bounds__(256) void bc_kernel(const float* __restrict__ x,
                                                 const float* __restrict__ d,
                                                 const float* __restrict__ bias,
                                                 const float2* __restrict__ Wc,
                                                 float* __restrict__ out)
{
    __shared__ float Ar[4096], Ai[4096], Br[4096], Bi[4096];
    __shared__ float tabr[256], tabi[256];
    int t = threadIdx.x;
    int b = blockIdx.x;

    float sv, cv;
    sincosf((float)t * (TWO_PI / 256.0f), &sv, &cv);
    tabr[t] = cv; tabi[t] = sv;

    // Load row, fold in d (+/-1), imag = 0. Coalesced float4.
    const float4* x4 = (const float4*)(x + (size_t)b * DDIM);
    const float4* d4 = (const float4*)d;
#pragma unroll
    for (int u = 0; u < 4; ++u) {
        int idx = u * 256 + t;
        float4 xv = x4[idx], dv = d4[idx];
        int l = idx * 4;
        Ar[l]     = xv.x * dv.x;
        Ar[l + 1] = xv.y * dv.y;
        Ar[l + 2] = xv.z * dv.z;
        Ar[l + 3] = xv.w * dv.w;
        Ai[l] = 0.f; Ai[l + 1] = 0.f; Ai[l + 2] = 0.f; Ai[l + 3] = 0.f;
    }
    __syncthreads();

    // Forward FFT (e^{-i}): A -> B -> A -> B -> A
    fft_stage4<1, 0>(Ar, Ai, Br, Bi, tabr, tabi, t, 1.f);  __syncthreads();
    fft_stage4<4, 2>(Br, Bi, Ar, Ai, tabr, tabi, t, 1.f);  __syncthreads();
    fft_stage4<16, 4>(Ar, Ai, Br, Bi, tabr, tabi, t, 1.f); __syncthreads();
    fft_stage4<64, 6>(Br, Bi, Ar, Ai, tabr, tabi, t, 1.f); __syncthreads();

    // Frequency-domain matmul, thread t owns frequency f = t (f <= 128).
    // Y[i][f] = sum_j X[j][f] * Wc[f][i][j]; in-place column update is safe
    // (thread t only ever reads/writes column t; conj goes to unread cols).
    if (t <= 128) {
        float xr[16], xi[16];
#pragma unroll
        for (int j = 0; j < 16; ++j) { xr[j] = Ar[j * 256 + t]; xi[j] = Ai[j * 256 + t]; }
        const float4* wrow = (const float4*)(Wc + t * 256);
#pragma unroll
        for (int i = 0; i < 16; ++i) {
            float yr = 0.f, yi = 0.f;
#pragma unroll
            for (int jj = 0; jj < 8; ++jj) {
                float4 wv = wrow[i * 8 + jj];
                int j0 = 2 * jj;
                yr += xr[j0] * wv.x - xi[j0] * wv.y;
                yi += xr[j0] * wv.y + xi[j0] * wv.x;
                yr += xr[j0 + 1] * wv.z - xi[j0 + 1] * wv.w;
                yi += xr[j0 + 1] * wv.w + xi[j0 + 1] * wv.z;
            }
            Ar[i * 256 + t] = yr;
            Ai[i * 256 + t] = yi;
            if (t >= 1 && t <= 127) {            // conjugate symmetry fills f>128
                Ar[i * 256 + 256 - t] = yr;
                Ai[i * 256 + 256 - t] = -yi;
            }
        }
    }
    __syncthreads();

    // Inverse FFT (e^{+i}, unnormalized): A -> B -> A -> B -> A
    fft_stage4<1, 0>(Ar, Ai, Br, Bi, tabr, tabi, t, -1.f);  __syncthreads();
    fft_stage4<4, 2>(Br, Bi, Ar, Ai, tabr, tabi, t, -1.f);  __syncthreads();
    fft_stage4<16, 4>(Ar, Ai, Br, Bi, tabr, tabi, t, -1.f); __syncthreads();
    fft_stage4<64, 6>(Br, Bi, Ar, Ai, tabr, tabi, t, -1.f); __syncthreads();

    // Write real part / 256 + bias, coalesced float4.
    float* op = out + (size_t)b * DDIM;
    const float4* b4 = (const float4*)bias;
#pragma unroll
    for (int u = 0; u < 4; ++u) {
        int idx = u * 256 + t;
        int l = idx * 4;
        float4 bv = b4[idx];
        float4 ov;
        ov.x = Ar[l]     * (1.f / 256.f) + bv.x;
        ov.y = Ar[l + 1] * (1.f / 256.f) + bv.y;
        ov.z = Ar[l + 2] * (1.f / 256.f) + bv.z;
        ov.w = Ar[l + 3] * (1.f / 256.f) + bv.w;
        ((float4*)op)[idx] = ov;
    }
}

extern "C" void kernel_launch(void* const* d_in, const int* in_sizes, int n_in,
                              void* d_out, int out_size, void* d_ws, size_t ws_size,
                              hipStream_t stream)
{
    const float* x    = (const float*)d_in[0];   // (8192, 4096)
    const float* W    = (const float*)d_in[1];   // (16, 16, 256)
    const float* d    = (const float*)d_in[2];   // (4096,)
    const float* bias = (const float*)d_in[3];   // (4096,)
    float* out = (float*)d_out;
    float2* Wc = (float2*)d_ws;                  // [129][16][16] complex

    wfft_kernel<<<256, 256, 0, stream>>>(W, Wc);
    bc_kernel<<<BATCH, 256, 0, stream>>>(x, d, bias, Wc, out);
}